// Round 5
// baseline (571.752 us; speedup 1.0000x reference)
//
#include <hip/hip_runtime.h>

#define KD 25088   // 512*49
#define N_DIM 1000
#define ZS 28      // split-K factor

typedef __attribute__((ext_vector_type(8))) short bf16x8;
typedef __attribute__((ext_vector_type(4))) float f32x4;

// v_cvt_pk_bf16_f32: dst.lo=bf16(a), dst.hi=bf16(b) — RNE, 1 inst [T12, m214v22]
__device__ inline unsigned pack2(float a, float b) {
  unsigned r;
  asm("v_cvt_pk_bf16_f32 %0, %1, %2" : "=v"(r) : "v"(a), "v"(b));
  return r;
}
__device__ inline unsigned short f2bf(float x) {
  unsigned r;
  asm("v_cvt_pk_bf16_f32 %0, %1, %1" : "=v"(r) : "v"(x));
  return (unsigned short)r;
}
__device__ inline float bf2f(unsigned short u) {
  union { unsigned u; float f; } v; v.u = ((unsigned)u) << 16; return v.f;
}

// ---------------------------------------------------------------------------
// fallback-only: outR[m,n] = bias[n]
// ---------------------------------------------------------------------------
__global__ __launch_bounds__(256) void init_bias_k(
    const float* __restrict__ bias, float* __restrict__ outR) {
  const int id = blockIdx.x * 256 + threadIdx.x;
  if (id < 256 * N_DIM) outR[id] = bias[id % N_DIM];
}

// ---------------------------------------------------------------------------
// R-GEMM: fixed 28-way split-K. ATOMIC=1: fp32 atomics into outR (fallback).
// ATOMIC=0: non-atomic stores into partials ws [z][m][n].
// 128x128 tile, BK=32, 4 waves, double-buffered LDS, v_cvt_pk bf16 staging.
// XCD swizzle with m in the LOW bit of the per-XCD tile index (mzp = z*2+m):
// the two m-blocks sharing a W-slice (n,z) are 8 ids apart on the SAME XCD,
// co-dispatched -> W-slice L2-served once (was: fetched on 2 XCDs). The 8
// n-blocks sharing an A-slice stay adjacent as before.
// ---------------------------------------------------------------------------
template<int ATOMIC>
__global__ __launch_bounds__(256) void rgemm_k(
    const float* __restrict__ A, const float* __restrict__ W,
    float* __restrict__ D) {
  __shared__ unsigned short As[2][128 * 32];
  __shared__ unsigned short Bs[2][128 * 32];
  const int t = threadIdx.x;
  // bijective decode: xcd = id&7; loc = id>>3; mzp = xcd*7 + (loc>>3);
  // n = loc&7; m = mzp&1; z = mzp>>1
  const int id  = blockIdx.x;          // 0..447
  const int loc = id >> 3;             // 0..55
  const int mzp = (id & 7) * 7 + (loc >> 3);   // 0..55
  const int n0  = (loc & 7) * 128;
  const int m0  = (mzp & 1) * 128;
  const int z   = mzp >> 1;            // 0..27
  const int lane = t & 63, w = t >> 6;
  const int cw = (w >> 1) * 64, jw = (w & 1) * 64;
  const int r16 = lane & 15, quad = lane >> 4;
  const int srow = t >> 2;           // 0..63
  const int sc8  = (t & 3) << 3;     // 0,8,16,24
  const bool doj3 = (n0 + jw + 48) < N_DIM;   // j=3 fragment fully pad?

  float a_pre[16], b_pre[16];

  f32x4 acc[4][4];
#pragma unroll
  for (int i = 0; i < 4; ++i)
#pragma unroll
    for (int j = 0; j < 4; ++j) {
      acc[i][j][0] = 0.f; acc[i][j][1] = 0.f;
      acc[i][j][2] = 0.f; acc[i][j][3] = 0.f;
    }

#define RG_LOAD(s_)                                                         \
  {                                                                         \
    const int kbase = ((z) * ZS + (s_)) * 32;                               \
    _Pragma("unroll")                                                       \
    for (int h = 0; h < 2; ++h) {                                           \
      const int row = h * 64 + srow;                                        \
      const float* pa = A + (size_t)(m0 + row) * KD + kbase + sc8;          \
      *(float4*)&a_pre[h * 8 + 0] = *(const float4*)pa;                     \
      *(float4*)&a_pre[h * 8 + 4] = *(const float4*)(pa + 4);               \
      const int wr = n0 + row;                                              \
      if (wr < N_DIM) {                                                     \
        const float* pw = W + (size_t)wr * KD + kbase + sc8;                \
        *(float4*)&b_pre[h * 8 + 0] = *(const float4*)pw;                   \
        *(float4*)&b_pre[h * 8 + 4] = *(const float4*)(pw + 4);             \
      } else {                                                              \
        _Pragma("unroll")                                                   \
        for (int q = 0; q < 8; ++q) b_pre[h * 8 + q] = 0.f;                 \
      }                                                                     \
    }                                                                       \
  }

#define RG_WRITE(p_)                                                        \
  {                                                                         \
    _Pragma("unroll")                                                       \
    for (int h = 0; h < 2; ++h) {                                           \
      const int row = h * 64 + srow;                                        \
      uint4 ua, ub;                                                         \
      ua.x = pack2(a_pre[h*8+0], a_pre[h*8+1]);                             \
      ua.y = pack2(a_pre[h*8+2], a_pre[h*8+3]);                             \
      ua.z = pack2(a_pre[h*8+4], a_pre[h*8+5]);                             \
      ua.w = pack2(a_pre[h*8+6], a_pre[h*8+7]);                             \
      ub.x = pack2(b_pre[h*8+0], b_pre[h*8+1]);                             \
      ub.y = pack2(b_pre[h*8+2], b_pre[h*8+3]);                             \
      ub.z = pack2(b_pre[h*8+4], b_pre[h*8+5]);                             \
      ub.w = pack2(b_pre[h*8+6], b_pre[h*8+7]);                             \
      *(uint4*)&As[p_][row * 32 + sc8] = ua;                                \
      *(uint4*)&Bs[p_][row * 32 + sc8] = ub;                                \
    }                                                                       \
  }

  RG_LOAD(0); RG_WRITE(0); __syncthreads();
  int p = 0;
  for (int s = 0; s < ZS; ++s) {
    if (s + 1 < ZS) RG_LOAD(s + 1);
    bf16x8 af[4], bq[4];
#pragma unroll
    for (int i = 0; i < 4; ++i) {
      af[i] = *(const bf16x8*)&As[p][(cw + i * 16 + r16) * 32 + quad * 8];
      if (i < 3 || doj3)
        bq[i] = *(const bf16x8*)&Bs[p][(jw + i * 16 + r16) * 32 + quad * 8];
    }
#pragma unroll
    for (int i = 0; i < 4; ++i)
#pragma unroll
      for (int j = 0; j < 4; ++j)
        if (j < 3 || doj3)
          acc[i][j] = __builtin_amdgcn_mfma_f32_16x16x32_bf16(af[i], bq[j], acc[i][j], 0, 0, 0);
    if (s + 1 < ZS) RG_WRITE(p ^ 1);
    __syncthreads();
    p ^= 1;
  }

  // epilogue: C layout col=lane&15 (n), row=quad*4+r (m)   [m89-verified]
#pragma unroll
  for (int j = 0; j < 4; ++j) {
    const int n = n0 + jw + j * 16 + r16;
    if (n < N_DIM) {
#pragma unroll
      for (int i = 0; i < 4; ++i)
#pragma unroll
        for (int r = 0; r < 4; ++r) {
          const int m = m0 + cw + i * 16 + quad * 4 + r;
          if (ATOMIC)
            atomicAdd(&D[(size_t)m * N_DIM + n], acc[i][j][r]);
          else
            D[((size_t)z * 256 + m) * N_DIM + n] = acc[i][j][r];
        }
    }
  }
#undef RG_LOAD
#undef RG_WRITE
}

// ---------------------------------------------------------------------------
// FUSED fast-path chain: reduce(part)+bias -> outR; top-8; exact re-dot for
// flagged rows; final top-2. One 256-thread block per sample n.
//   Phase A: 250 threads reduce 28 z-planes (float4, coalesced) -> LDS row+outR
//   Phase B: wave 0 runs the top-8 (identical tie-break semantics)
//   Phase C: if flagged, 4 waves compute 8 exact fp32 dots (2 each)
//   Phase D: thread 0 final select from exact dots
// ---------------------------------------------------------------------------
__global__ __launch_bounds__(256) void rtop_k(
    const float* __restrict__ part, const float* __restrict__ A,
    const float* __restrict__ W, const float* __restrict__ bias,
    float* __restrict__ outR, int* __restrict__ top2,
    float* __restrict__ outSPD) {
  __shared__ float row[1024];
  __shared__ float cvs[8];
  __shared__ int   cis[8];
  __shared__ float dots[8];
  __shared__ int   flag_s;
  const int n = blockIdx.x;
  const int t = threadIdx.x;

  // Phase A
  if (t < 250) {
    const int e0 = t * 4;
    float4 acc = *(const float4*)(bias + e0);
#pragma unroll
    for (int z = 0; z < ZS; ++z) {
      const float4 pv = *(const float4*)(part + ((size_t)z * 256 + n) * N_DIM + e0);
      acc.x += pv.x; acc.y += pv.y; acc.z += pv.z; acc.w += pv.w;
    }
    *(float4*)(row + e0) = acc;
    *(float4*)(outR + (size_t)n * N_DIM + e0) = acc;
  }
  __syncthreads();

  // Phase B (wave 0 only) — identical algorithm to the old top8_k
  if (t < 64) {
    const int lane = t;
    float v[16];
#pragma unroll
    for (int r = 0; r < 16; ++r) {
      const int o = lane + r * 64;
      v[r] = (o < N_DIM) ? row[o] : -3.0e38f;
    }
    float cv[8]; int ci[8];
#pragma unroll
    for (int rr = 0; rr < 8; ++rr) {
      float bv = -3.0e38f; int bi = 0x3fffffff;
#pragma unroll
      for (int r = 0; r < 16; ++r) {
        const int o = lane + r * 64;
        if (v[r] > bv || (v[r] == bv && o < bi)) { bv = v[r]; bi = o; }
      }
#pragma unroll
      for (int off = 32; off >= 1; off >>= 1) {
        const float ov = __shfl_xor(bv, off, 64);
        const int   oi = __shfl_xor(bi, off, 64);
        if (ov > bv || (ov == bv && oi < bi)) { bv = ov; bi = oi; }
      }
      cv[rr] = bv; ci[rr] = bi;
#pragma unroll
      for (int r = 0; r < 16; ++r)
        if (lane + r * 64 == bi) v[r] = -3.0e38f;
    }
    if (lane == 0) {
      const bool safe = (cv[0] - cv[1] >= 0.025f) &&
                        (cv[1] - cv[2] >= 0.025f) &&
                        (cv[1] - cv[7] >= 0.05f);
      flag_s = safe ? 0 : 1;
      top2[2 * n]     = ci[0];
      top2[2 * n + 1] = ci[1];
#pragma unroll
      for (int r = 0; r < 8; ++r) { cis[r] = ci[r]; cvs[r] = cv[r]; }
      outSPD[4 * n + 0] = 0.f; outSPD[4 * n + 1] = 0.f;
      outSPD[4 * n + 2] = 0.f; outSPD[4 * n + 3] = 0.f;
    }
  }
  __syncthreads();

  // Phase C: exact dots (waves 0..3 handle 2 candidates each)
  if (flag_s) {
    const int lane = t & 63, w = t >> 6;
    const float4* a4 = (const float4*)(A + (size_t)n * KD);
    for (int cc = w; cc < 8; cc += 4) {
      const int idx = cis[cc];
      const float4* w4 = (const float4*)(W + (size_t)idx * KD);
      float s = 0.f;
      for (int i = lane; i < KD / 4; i += 64) {
        const float4 av = a4[i];
        const float4 wv = w4[i];
        s += av.x * wv.x + av.y * wv.y + av.z * wv.z + av.w * wv.w;
      }
#pragma unroll
      for (int off = 32; off >= 1; off >>= 1) s += __shfl_xor(s, off, 64);
      if (lane == 0) dots[cc] = s + bias[idx];
    }
  }
  __syncthreads();

  // Phase D: final select (exact values) — same tie-break as old select_k
  if (flag_s && t == 0) {
    int b0 = -1; float v0 = -3.0e38f; int i0 = 0x3fffffff;
    for (int c = 0; c < 8; ++c) {
      const int idx = cis[c];
      const float vv = dots[c];
      if (vv > v0 || (vv == v0 && idx < i0)) { v0 = vv; i0 = idx; b0 = c; }
    }
    float v1 = -3.0e38f; int i1 = 0x3fffffff;
    for (int c = 0; c < 8; ++c) {
      if (c == b0) continue;
      const int idx = cis[c];
      const float vv = dots[c];
      if (vv > v1 || (vv == v1 && idx < i1)) { v1 = vv; i1 = idx; }
    }
    top2[2 * n]     = i0;
    top2[2 * n + 1] = i1;
  }
}

// ---------------------------------------------------------------------------
// fallback-only kernels: top8 / rdot / select (read outR path)
// ---------------------------------------------------------------------------
__global__ __launch_bounds__(64) void top8_k(
    const float* __restrict__ outR, int* __restrict__ top2,
    int* __restrict__ candIdx, int* __restrict__ flags,
    float* __restrict__ outSPD) {
  const int n = blockIdx.x;
  const int lane = threadIdx.x;
  float v[16];
#pragma unroll
  for (int r = 0; r < 16; ++r) {
    const int o = lane + r * 64;
    v[r] = (o < N_DIM) ? outR[(size_t)n * N_DIM + o] : -3.0e38f;
  }
  float cv[8]; int ci[8];
#pragma unroll
  for (int rr = 0; rr < 8; ++rr) {
    float bv = -3.0e38f; int bi = 0x3fffffff;
#pragma unroll
    for (int r = 0; r < 16; ++r) {
      const int o = lane + r * 64;
      if (v[r] > bv || (v[r] == bv && o < bi)) { bv = v[r]; bi = o; }
    }
#pragma unroll
    for (int off = 32; off >= 1; off >>= 1) {
      const float ov = __shfl_xor(bv, off, 64);
      const int   oi = __shfl_xor(bi, off, 64);
      if (ov > bv || (ov == bv && oi < bi)) { bv = ov; bi = oi; }
    }
    cv[rr] = bv; ci[rr] = bi;
#pragma unroll
    for (int r = 0; r < 16; ++r)
      if (lane + r * 64 == bi) v[r] = -3.0e38f;
  }
  if (lane == 0) {
    const bool safe = (cv[0] - cv[1] >= 0.025f) &&
                      (cv[1] - cv[2] >= 0.025f) &&
                      (cv[1] - cv[7] >= 0.05f);
    flags[n] = safe ? 0 : 1;
    top2[2 * n]     = ci[0];
    top2[2 * n + 1] = ci[1];
#pragma unroll
    for (int r = 0; r < 8; ++r) candIdx[n * 8 + r] = ci[r];
    outSPD[4 * n + 0] = 0.f; outSPD[4 * n + 1] = 0.f;
    outSPD[4 * n + 2] = 0.f; outSPD[4 * n + 3] = 0.f;
  }
}

__global__ __launch_bounds__(256) void rdot_k(
    const float* __restrict__ A, const float* __restrict__ W,
    const float* __restrict__ bias, const int* __restrict__ candIdx,
    const int* __restrict__ flags, float* __restrict__ vals) {
  const int n = blockIdx.x;
  if (!flags[n]) return;
  const int c = blockIdx.y;
  const int idx = candIdx[n * 8 + c];
  const float4* a4 = (const float4*)(A + (size_t)n * KD);
  const float4* w4 = (const float4*)(W + (size_t)idx * KD);
  float s = 0.f;
  for (int i = threadIdx.x; i < KD / 4; i += 256) {
    const float4 av = a4[i];
    const float4 wv = w4[i];
    s += av.x * wv.x + av.y * wv.y + av.z * wv.z + av.w * wv.w;
  }
#pragma unroll
  for (int off = 32; off >= 1; off >>= 1) s += __shfl_xor(s, off, 64);
  __shared__ float red[4];
  const int lane = threadIdx.x & 63, w = threadIdx.x >> 6;
  if (lane == 0) red[w] = s;
  __syncthreads();
  if (threadIdx.x == 0)
    vals[n * 8 + c] = red[0] + red[1] + red[2] + red[3] + bias[idx];
}

__global__ __launch_bounds__(64) void select_k(
    const float* __restrict__ vals, const int* __restrict__ candIdx,
    const int* __restrict__ flags, int* __restrict__ top2) {
  const int n = blockIdx.x;
  if (threadIdx.x != 0 || !flags[n]) return;
  int b0 = -1; float v0 = -3.0e38f; int i0 = 0x3fffffff;
  for (int c = 0; c < 8; ++c) {
    const int idx = candIdx[n * 8 + c];
    const float vv = vals[n * 8 + c];
    if (vv > v0 || (vv == v0 && idx < i0)) { v0 = vv; i0 = idx; b0 = c; }
  }
  float v1 = -3.0e38f; int i1 = 0x3fffffff;
  for (int c = 0; c < 8; ++c) {
    if (c == b0) continue;
    const int idx = candIdx[n * 8 + c];
    const float vv = vals[n * 8 + c];
    if (vv > v1 || (vv == v1 && idx < i1)) { v1 = vv; i1 = idx; }
  }
  top2[2 * n]     = i0;
  top2[2 * n + 1] = i1;
}

// ---------------------------------------------------------------------------
// pack: block (n, which). Reads FINAL top2 (rtop_k already selected), packs
// W[sel] -> Wp[n][which*49+hw][c] (bf16) via coalesced float4 linear read +
// LDS transpose tile[hw][c] (stride 130) + coalesced 4B writes.
// ---------------------------------------------------------------------------
__global__ __launch_bounds__(256) void packsel_k(
    const float* __restrict__ W, const int* __restrict__ top2,
    unsigned short* __restrict__ Wp) {
  __shared__ unsigned short tile[49 * 130];
  const int n = blockIdx.x;
  const int which = blockIdx.y;        // 0 -> ia rows 0..48, 1 -> ib rows 49..97
  const int t = threadIdx.x;
  const int sel = top2[2 * n + which];
  unsigned short* dstn = Wp + (size_t)n * 65536;
  {
    // zero pad rows: which=0 -> 98..112, which=1 -> 113..127 (15 rows each)
    const int r0 = 98 + which * 15;
    for (int u = t; u < 15 * 128; u += 256) {
      const int rr = u >> 7;
      const int cc = (u & 127) << 1;
      *(unsigned*)(dstn + (size_t)(r0 + rr) * 512 + cc) = 0u;
    }
  }
  const float4* src4 = (const float4*)(W + (size_t)sel * KD);
  for (int chunk = 0; chunk < 4; ++chunk) {        // 128 c-rows per chunk
    const float4* s4 = src4 + chunk * 1568;
    for (int u4 = t; u4 < 1568; u4 += 256) {
      const float4 fv = s4[u4];
      const float vv[4] = {fv.x, fv.y, fv.z, fv.w};
      const int i0 = u4 * 4;
#pragma unroll
      for (int e = 0; e < 4; ++e) {
        const int idx = i0 + e;
        const int c = idx / 49;
        const int hw = idx - c * 49;
        tile[hw * 130 + c] = f2bf(vv[e]);
      }
    }
    __syncthreads();
    const int cp = t & 63, hwb = t >> 6;
    unsigned short* wbase = dstn + (size_t)which * 49 * 512 + chunk * 128 + 2 * cp;
#pragma unroll
    for (int it = 0; it < 13; ++it) {
      const int hw = hwb + it * 4;
      if (hw < 49) {
        const unsigned val = *(const unsigned*)&tile[hw * 130 + 2 * cp];
        *(unsigned*)(wbase + (size_t)hw * 512) = val;
      }
    }
    __syncthreads();
  }
}

// ---------------------------------------------------------------------------
// SPD fast path: per (n, c-tile 128): U = S_tile x Wp^T via bf16 MFMA.
// A (S, fp32 HBM stream) staged through LDS for coalescing [R3 lesson];
// B (Wp, bf16, L2-resident 128KB/n) read DIRECTLY from global in fragment
// layout. XCD swizzle: 4 c-blocks of one n consecutive on one XCD.
// jw==64 waves skip the all-pad j=3 fragment (rows 112..127 are zeros).
// ---------------------------------------------------------------------------
__global__ __launch_bounds__(256) void spd_k(
    const float* __restrict__ S, const unsigned short* __restrict__ Wp,
    float* __restrict__ outSPD) {
  __shared__ unsigned short As[2][128 * 32];
  __shared__ float red[4];
  const int t = threadIdx.x;
  // bijective decode: id -> (xcd=id&7, j=id>>3); n = xcd*32 + (j>>2); c = j&3
  const int id = blockIdx.x;           // 0..1023
  const int n  = (id & 7) * 32 + ((id >> 3) >> 2);
  const int c0 = ((id >> 3) & 3) * 128;
  const float* Sn = S + (size_t)n * 512 * 512;
  const unsigned short* Wpn = Wp + (size_t)n * 65536;
  const int lane = t & 63, w = t >> 6;
  const int cw = (w >> 1) * 64, jw = (w & 1) * 64;
  const int r16 = lane & 15, quad = lane >> 4;
  const int srow = t >> 2;
  const int sc8  = (t & 3) << 3;
  const bool doj3 = (jw == 0);         // jw==64: j=3 covers rows 112..127 (pad)

  if (t < 4) red[t] = 0.f;

  float a_pre[16];

  f32x4 acc[4][4];
#pragma unroll
  for (int i = 0; i < 4; ++i)
#pragma unroll
    for (int j = 0; j < 4; ++j) {
      acc[i][j][0] = 0.f; acc[i][j][1] = 0.f;
      acc[i][j][2] = 0.f; acc[i][j][3] = 0.f;
    }

  // loop-invariant B fragment bases (bf16, already in fragment layout)
  const unsigned short* wjb[4];
#pragma unroll
  for (int j = 0; j < 4; ++j)
    wjb[j] = Wpn + (size_t)(jw + j * 16 + r16) * 512 + quad * 8;

#define SP_LOAD(s_)                                                         \
  {                                                                         \
    const int d0 = (s_) * 32;                                               \
    _Pragma("unroll")                                                       \
    for (int h = 0; h < 2; ++h) {                                           \
      const int row = h * 64 + srow;                                        \
      const float* pa = Sn + (size_t)(c0 + row) * 512 + d0 + sc8;           \
      *(float4*)&a_pre[h * 8 + 0] = *(const float4*)pa;                     \
      *(float4*)&a_pre[h * 8 + 4] = *(const float4*)(pa + 4);               \
    }                                                                       \
  }

#define SP_WRITE(p_)                                                        \
  {                                                                         \
    _Pragma("unroll")                                                       \
    for (int h = 0; h < 2; ++h) {                                           \
      const int row = h * 64 + srow;                                        \
      uint4 ua;                                                             \
      ua.x = pack2(a_pre[h*8+0], a_pre[h*8+1]);                             \
      ua.y = pack2(a_pre[h*8+2], a_pre[h*8+3]);                             \
      ua.z = pack2(a_pre[h*8+4], a_pre[h*8+5]);                             \
      ua.w = pack2(a_pre[h*8+6], a_pre[h*8+7]);                             \
      *(uint4*)&As[p_][row * 32 + sc8] = ua;                                \
    }                                                                       \
  }

  SP_LOAD(0); SP_WRITE(0); __syncthreads();
  int p = 0;
  for (int s = 0; s < 16; ++s) {
    if (s + 1 < 16) SP_LOAD(s + 1);
    const int k0 = s * 32;
    bf16x8 af[4], bq[4];
#pragma unroll
    for (int i = 0; i < 4; ++i) {
      af[i] = *(const bf16x8*)&As[p][(cw + i * 16 + r16) * 32 + quad * 8];
      if (i < 3 || doj3)
        bq[i] = *(const bf16x8*)(wjb[i] + k0);
    }
#pragma unroll
    for (int i = 0; i < 4; ++i)
#pragma unroll
      for (int j = 0; j < 4; ++j)
        if (j < 3 || doj3)
          acc[i][j] = __builtin_amdgcn_mfma_f32_16x16x32_bf16(af[i], bq[j], acc[i][j], 0, 0, 0);
    if (s + 1 < 16) SP_WRITE(p ^ 1);
    __syncthreads();
    p ^= 1;
  }
#undef SP_LOAD
#undef SP_WRITE

  // fold: C layout col=lane&15 (j), row=quad*4+r (c)
  float p00 = 0.f, p01 = 0.f, p10 = 0.f, p11 = 0.f;
#pragma unroll
  for (int j = 0; j < 4; ++j) {
    const int jj = jw + j * 16 + r16;
    if (jj < 98) {
      const int kk = (jj >= 49);
      const int hw = jj - 49 * kk;
      const unsigned short* wa = Wpn + (size_t)hw * 512;         // W[ia][c,hw]
      const unsigned short* wb = Wpn + (size_t)(49 + hw) * 512;  // W[ib][c,hw]
#pragma unroll
      for (int i = 0; i < 4; ++i) {
#pragma unroll
        for (int r = 0; r < 4; ++r) {
          const int c = c0 + cw + i * 16 + quad * 4 + r;
          const float u   = acc[i][j][r];
          const float wav = bf2f(wa[c]);
          const float wbv = bf2f(wb[c]);
          if (kk == 0) { p00 = fmaf(u, wav, p00); p01 = fmaf(u, wbv, p01); }
          else         { p10 = fmaf(u, wav, p10); p11 = fmaf(u, wbv, p11); }
        }
      }
    }
  }

  atomicAdd(&red[0], p00);
  atomicAdd(&red[1], p01);
  atomicAdd(&red[2], p10);
  atomicAdd(&red[3], p11);
  __syncthreads();
  if (t < 4) atomicAdd(&outSPD[n * 4 + t], red[t]);
}

// ---------------------------------------------------------------------------
// SPD fallback (no workspace needed beyond the small scratch)
// ---------------------------------------------------------------------------
__global__ __launch_bounds__(256) void spd_fb_k(
    const float* __restrict__ S, const float* __restrict__ W,
    const int* __restrict__ top2, float* __restrict__ outSPD) {
  __shared__ unsigned short As[128 * 40];
  __shared__ unsigned short Bs[128 * 40];
  __shared__ float red[4];
  const int t = threadIdx.x;
  const int n  = blockIdx.x >> 2;
  const int c0 = (blockIdx.x & 3) * 128;
  const int ia = top2[2 * n];
  const int ib = top2[2 * n + 1];
  const float* Sn = S + (size_t)n * 512 * 512;
  const int lane = t & 63, w = t >> 6;
  const int cw = (w >> 1) * 64, jw = (w & 1) * 64;
  const int r16 = lane & 15, quad = lane >> 4;
  if (t < 4) red[t] = 0.f;
  f32x4 acc[4][4];
#pragma unroll
  for (int i = 0; i < 4; ++i)
#pragma unroll
    for (int j = 0; j < 4; ++j) {
      acc[i][j][0] = 0.f; acc[i][j][1] = 0.f;
      acc[i][j][2] = 0.f; acc[i][j][3] = 0.f;
    }
  const int bj  = t & 127;
  const int bh  = t >> 7;
  const int bkk = (bj >= 49);
  const int bhw = bj - 49 * bkk;
  const bool bvalid = (bj < 98);
  const float* brow = W + (size_t)(bkk ? ib : ia) * KD + bhw;
  for (int d0 = 0; d0 < 512; d0 += 32) {
#pragma unroll
    for (int h = 0; h < 4; ++h) {
      const int idx = h * 256 + t;
      const int row = idx >> 3;
      const int c4  = (idx & 7) << 2;
      float4 av = *(const float4*)(Sn + (size_t)(c0 + row) * 512 + d0 + c4);
      uint2 pa;
      pa.x = pack2(av.x, av.y);
      pa.y = pack2(av.z, av.w);
      *(uint2*)&As[row * 40 + c4] = pa;
    }
#pragma unroll
    for (int dd2 = 0; dd2 < 16; dd2 += 2) {
      const int dd = bh * 16 + dd2;
      const float x0 = bvalid ? brow[(size_t)(d0 + dd) * 49] : 0.f;
      const float x1 = bvalid ? brow[(size_t)(d0 + dd + 1) * 49] : 0.f;
      *(unsigned*)&Bs[bj * 40 + dd] = pack2(x0, x1);
    }
    __syncthreads();
    bf16x8 af[4], bq[4];
#pragma unroll
    for (int i = 0; i < 4; ++i) {
      af[i] = *(const bf16x8*)&As[(cw + i * 16 + r16) * 40 + quad * 8];
      bq[i] = *(const bf16x8*)&Bs[(jw + i * 16 + r16) * 40 + quad * 8];
    }
#pragma unroll
    for (int i = 0; i < 4; ++i)
#pragma unroll
      for (int j = 0; j < 4; ++j)
        acc[i][j] = __builtin_amdgcn_mfma_f32_16x16x32_bf16(af[i], bq[j], acc[i][j], 0, 0, 0);
    __syncthreads();
  }
  float p00 = 0.f, p01 = 0.f, p10 = 0.f, p11 = 0.f;
  const float* Wa = W + (size_t)ia * KD;
  const float* Wb = W + (size_t)ib * KD;
#pragma unroll
  for (int j = 0; j < 4; ++j) {
    const int jj = jw + j * 16 + r16;
    if (jj < 98) {
      const int kk = (jj >= 49);
      const int hw = jj - 49 * kk;
#pragma unroll
      for (int i = 0; i < 4; ++i)
#pragma unroll
        for (int r = 0; r < 4; ++r) {
          const int c = c0 + cw + i * 16 + quad * 4 + r;
          const float u  = acc[i][j][r];
          const float wa = Wa[(size_t)c * 49 + hw];
          const float wb = Wb[(size_t)c * 49 + hw];
          if (kk == 0) { p00 = fmaf(u, wa, p00); p01 = fmaf(u, wb, p01); }
          else         { p10 = fmaf(u, wa, p10); p11 = fmaf(u, wb, p11); }
        }
    }
  }
  atomicAdd(&red[0], p00);
  atomicAdd(&red[1], p01);
  atomicAdd(&red[2], p10);
  atomicAdd(&red[3], p11);
  __syncthreads();
  if (t < 4) atomicAdd(&outSPD[n * 4 + t], red[t]);
}

// ---------------------------------------------------------------------------
extern "C" void kernel_launch(void* const* d_in, const int* in_sizes, int n_in,
                              void* d_out, int out_size, void* d_ws, size_t ws_size,
                              hipStream_t stream) {
  const float* inputR   = (const float*)d_in[0];
  const float* inputSPD = (const float*)d_in[1];
  const float* weight   = (const float*)d_in[2];
  const float* bias     = (const float*)d_in[3];
  float* out = (float*)d_out;

  // ws: [top2 2K][cand 8K][flags 1K][vals 8K] .. 64K ..
  //     [part 28*256*1000*4 = 28.672 MB][Wp 33.55 MB]
  int*   top2    = (int*)d_ws;
  int*   candIdx = (int*)((char*)d_ws + 2048);
  int*   flags   = (int*)((char*)d_ws + 2048 + 8192);
  float* vals    = (float*)((char*)d_ws + 2048 + 8192 + 1024);
  float* part    = (float*)((char*)d_ws + 65536);
  const size_t PART_BYTES = (size_t)ZS * 256 * N_DIM * 4;          // 28,672,000
  unsigned short* Wp = (unsigned short*)((char*)d_ws + 65536 + PART_BYTES);
  const bool bigws = ws_size >= 65536ull + PART_BYTES + 256ull * 65536ull * 2ull;

  if (bigws) {
    rgemm_k<0><<<dim3(448), 256, 0, stream>>>(inputR, weight, part);
    rtop_k<<<dim3(256), 256, 0, stream>>>(part, inputR, weight, bias, out, top2, out + 256000);
    packsel_k<<<dim3(256, 2), 256, 0, stream>>>(weight, top2, Wp);
    spd_k<<<dim3(1024), 256, 0, stream>>>(inputSPD, Wp, out + 256000);
  } else {
    init_bias_k<<<dim3(1000), 256, 0, stream>>>(bias, out);
    rgemm_k<1><<<dim3(448), 256, 0, stream>>>(inputR, weight, out);
    top8_k<<<dim3(256), 64, 0, stream>>>(out, top2, candIdx, flags, out + 256000);
    rdot_k<<<dim3(256, 8), 256, 0, stream>>>(inputR, weight, bias, candIdx, flags, vals);
    select_k<<<dim3(256), 64, 0, stream>>>(vals, candIdx, flags, top2);
    spd_fb_k<<<dim3(1024), 256, 0, stream>>>(inputSPD, weight, top2, out + 256000);
  }
}